// Round 2
// 1622.974 us; speedup vs baseline: 1.2856x; 1.2856x over previous
//
#include <hip/hip_runtime.h>
#include <math.h>

#define NA_  500000
#define NC_  250000
#define NE_  1000000
#define DD   256
#define NH   4
#define CC   64
#define NG   2048      // graphs

typedef unsigned short ushort_t;
typedef __attribute__((ext_vector_type(8))) short bf16x8;
typedef __attribute__((ext_vector_type(4))) float f32x4;

__device__ inline float bf2f(ushort_t u) {
    union { unsigned u; float f; } v; v.u = ((unsigned)u) << 16; return v.f;
}
__device__ inline ushort_t f2bf(float f) {
    union { float f; unsigned u; } v; v.f = f;
    unsigned r = v.u + 0x7fffu + ((v.u >> 16) & 1u);
    return (ushort_t)(r >> 16);
}

// ---------------- CSR build ----------------
__global__ void k_hist(const int* __restrict__ col, int* __restrict__ cnt) {
    int e = blockIdx.x * blockDim.x + threadIdx.x;
    if (e < NE_) atomicAdd(&cnt[col[e]], 1);
}

#define SCAN_T 256
#define SCAN_I 4
#define SCAN_TILE 1024
#define SCAN_NB ((NC_ + SCAN_TILE - 1) / SCAN_TILE)   // 245

__global__ void k_scan1(const int* __restrict__ cnt, int* __restrict__ bsums) {
    __shared__ int sm[SCAN_T];
    int t = threadIdx.x, b = blockIdx.x;
    int base = b * SCAN_TILE + t * SCAN_I;
    int s = 0;
#pragma unroll
    for (int j = 0; j < SCAN_I; ++j) { int i = base + j; if (i < NC_) s += cnt[i]; }
    sm[t] = s; __syncthreads();
    for (int off = SCAN_T / 2; off > 0; off >>= 1) {
        if (t < off) sm[t] += sm[t + off];
        __syncthreads();
    }
    if (t == 0) bsums[b] = sm[0];
}

__global__ void k_scan2(int* __restrict__ bsums, int nb) {
    __shared__ int sm[SCAN_T];
    int t = threadIdx.x;
    int v = (t < nb) ? bsums[t] : 0;
    sm[t] = v; __syncthreads();
    for (int off = 1; off < SCAN_T; off <<= 1) {
        int u = (t >= off) ? sm[t - off] : 0;
        __syncthreads();
        sm[t] += u;
        __syncthreads();
    }
    if (t < nb) bsums[t] = sm[t] - v;   // exclusive
}

__global__ void k_scan3(const int* __restrict__ cnt, const int* __restrict__ bsums,
                        int* __restrict__ offsets) {
    __shared__ int sm[SCAN_T];
    int t = threadIdx.x, b = blockIdx.x;
    int base = b * SCAN_TILE + t * SCAN_I;
    int c[SCAN_I]; int s = 0;
#pragma unroll
    for (int j = 0; j < SCAN_I; ++j) { int i = base + j; c[j] = (i < NC_) ? cnt[i] : 0; s += c[j]; }
    sm[t] = s; __syncthreads();
    for (int off = 1; off < SCAN_T; off <<= 1) {
        int u = (t >= off) ? sm[t - off] : 0;
        __syncthreads();
        sm[t] += u;
        __syncthreads();
    }
    int run = sm[t] - s + bsums[b];
#pragma unroll
    for (int j = 0; j < SCAN_I; ++j) { int i = base + j; if (i < NC_) offsets[i] = run; run += c[j]; }
    if (b == 0 && t == 0) offsets[NC_] = NE_;
}

__global__ void k_scatter(const int* __restrict__ row, const int* __restrict__ col,
                          const int* __restrict__ offsets, int* __restrict__ cursor,
                          int* __restrict__ edge_atom) {
    int e = blockIdx.x * blockDim.x + threadIdx.x;
    if (e < NE_) {
        int c = col[e];
        int p = atomicAdd(&cursor[c], 1);
        edge_atom[offsets[c] + p] = row[e];
    }
}

// ---------------- scatter-mean: one wave per clique ----------------
__global__ __launch_bounds__(256) void k_mean(const float* __restrict__ x,
                                              const int* __restrict__ offsets,
                                              const int* __restrict__ edge_atom,
                                              ushort_t* __restrict__ hx) {
    int wid = threadIdx.x >> 6, lane = threadIdx.x & 63;
    int c = blockIdx.x * 4 + wid;
    if (c >= NC_) return;
    int s = offsets[c], e = offsets[c + 1];
    float4 acc = make_float4(0.f, 0.f, 0.f, 0.f);
    for (int j = s; j < e; ++j) {
        int a = edge_atom[j];
        float4 v = *reinterpret_cast<const float4*>(x + (size_t)a * DD + lane * 4);
        acc.x += v.x; acc.y += v.y; acc.z += v.z; acc.w += v.w;
    }
    int n = e - s; if (n < 1) n = 1;
    float inv = 1.0f / (float)n;
    ushort4 o;
    o.x = f2bf(acc.x * inv); o.y = f2bf(acc.y * inv);
    o.z = f2bf(acc.z * inv); o.w = f2bf(acc.w * inv);
    *reinterpret_cast<ushort4*>(hx + (size_t)c * DD + lane * 4) = o;
}

// ---------------- xc = x_clique + relu(hx @ Wp + bp)  (f32 tiled) ----------------
#define BM 64
#define BN 64
#define BK 16
__global__ __launch_bounds__(256) void k_gemm(const ushort_t* __restrict__ hx,
                                              const float* __restrict__ Wp,
                                              const float* __restrict__ bp,
                                              const float* __restrict__ x_clique,
                                              float* __restrict__ xc) {
    __shared__ float As[BK][BM + 4];
    __shared__ float Bs[BK][BN + 4];
    int tid = threadIdx.x;
    int tx = tid & 15, ty = tid >> 4;
    int bm = blockIdx.y * BM;
    int bn = blockIdx.x * BN;
    float acc[4][4];
#pragma unroll
    for (int i = 0; i < 4; ++i)
#pragma unroll
        for (int j = 0; j < 4; ++j) acc[i][j] = 0.f;

    for (int kt = 0; kt < DD; kt += BK) {
        {   // A tile: 64 rows x 16 k (bf16 -> f32)
            int l = tid * 4;
            int ml = l >> 4;
            int kl = l & 15;
            int m = bm + ml;
            if (m < NC_) {
                ushort4 a4 = *reinterpret_cast<const ushort4*>(hx + (size_t)m * DD + kt + kl);
                As[kl + 0][ml] = bf2f(a4.x);
                As[kl + 1][ml] = bf2f(a4.y);
                As[kl + 2][ml] = bf2f(a4.z);
                As[kl + 3][ml] = bf2f(a4.w);
            } else {
                As[kl + 0][ml] = 0.f; As[kl + 1][ml] = 0.f;
                As[kl + 2][ml] = 0.f; As[kl + 3][ml] = 0.f;
            }
        }
        {   // B tile: 16 k x 64 n
            int l = tid * 4;
            int nl = l & 63;
            int kl = l >> 6;
            float4 b4 = *reinterpret_cast<const float4*>(Wp + (size_t)(kt + kl) * DD + bn + nl);
            *reinterpret_cast<float4*>(&Bs[kl][nl]) = b4;
        }
        __syncthreads();
#pragma unroll
        for (int k = 0; k < BK; ++k) {
            float4 av = *reinterpret_cast<const float4*>(&As[k][ty * 4]);
            float4 bv = *reinterpret_cast<const float4*>(&Bs[k][tx * 4]);
            float a[4] = {av.x, av.y, av.z, av.w};
            float b[4] = {bv.x, bv.y, bv.z, bv.w};
#pragma unroll
            for (int i = 0; i < 4; ++i)
#pragma unroll
                for (int j = 0; j < 4; ++j) acc[i][j] += a[i] * b[j];
        }
        __syncthreads();
    }
#pragma unroll
    for (int i = 0; i < 4; ++i) {
        int m = bm + ty * 4 + i;
        if (m >= NC_) continue;
        int n = bn + tx * 4;
        float4 bpv = *reinterpret_cast<const float4*>(bp + n);
        float4 xcv = *reinterpret_cast<const float4*>(x_clique + (size_t)m * DD + n);
        float4 o;
        o.x = xcv.x + fmaxf(acc[i][0] + bpv.x, 0.f);
        o.y = xcv.y + fmaxf(acc[i][1] + bpv.y, 0.f);
        o.z = xcv.z + fmaxf(acc[i][2] + bpv.z, 0.f);
        o.w = xcv.w + fmaxf(acc[i][3] + bpv.w, 0.f);
        *reinterpret_cast<float4*>(xc + (size_t)m * DD + n) = o;
    }
}

// ---------------- per-head MLP score via MFMA ----------------
// 4 head-GEMMs: [Nc,64] x [64,128] -> relu -> dot W2 -> score[Nc,4].
// Block = 256 thr (4 waves). Block owns 64 clique rows; wave w owns head w
// (columns w*64..w*64+63 of the xc row = head w's sc segment).
#define SROWS 64
#define SSTRIDE 264   // 256 + 8 ushorts => 528B row stride (16B aligned, breaks pow2 banks)

__global__ __launch_bounds__(256) void k_score(const float* __restrict__ xc,
                                               const float* __restrict__ W1,
                                               const float* __restrict__ b1,
                                               const float* __restrict__ W2,
                                               const float* __restrict__ b2,
                                               float* __restrict__ score) {
    __shared__ __align__(16) ushort_t sA[SROWS * SSTRIDE];
    int t = threadIdx.x;
    int R = blockIdx.x * SROWS;

    // stage xc tile: 64 rows x 256 f32 -> bf16 LDS (fully coalesced 32B/thread)
#pragma unroll
    for (int it = 0; it < 8; ++it) {
        int c = t + it * 256;       // chunk id 0..2047 (16B bf16 chunks)
        int r = c >> 5;             // row 0..63
        int ch = c & 31;            // chunk-in-row (8 cols each)
        int g = R + r;
        bf16x8 pk;
        if (g < NC_) {
            const float4* src = reinterpret_cast<const float4*>(xc + (size_t)g * DD + ch * 8);
            float4 v0 = src[0];
            float4 v1 = src[1];
            pk[0] = (short)f2bf(v0.x); pk[1] = (short)f2bf(v0.y);
            pk[2] = (short)f2bf(v0.z); pk[3] = (short)f2bf(v0.w);
            pk[4] = (short)f2bf(v1.x); pk[5] = (short)f2bf(v1.y);
            pk[6] = (short)f2bf(v1.z); pk[7] = (short)f2bf(v1.w);
        } else {
#pragma unroll
            for (int j = 0; j < 8; ++j) pk[j] = 0;
        }
        *reinterpret_cast<bf16x8*>(&sA[r * SSTRIDE + ch * 8]) = pk;
    }
    __syncthreads();

    int lane = t & 63;
    int w = t >> 6;          // head index
    int lr = lane & 15;      // row within M-tile / col within N-tile
    int lg = lane >> 4;      // k-group

    // A fragments: 4 M-tiles x 2 K-steps (K=64), layout: row=lane&15, k=8*(lane>>4)+j
    bf16x8 afr[4][2];
#pragma unroll
    for (int mt = 0; mt < 4; ++mt)
#pragma unroll
        for (int ks = 0; ks < 2; ++ks)
            afr[mt][ks] = *reinterpret_cast<const bf16x8*>(
                &sA[(mt * 16 + lr) * SSTRIDE + w * 64 + ks * 32 + lg * 8]);

    float sacc[4][4];
#pragma unroll
    for (int mt = 0; mt < 4; ++mt)
#pragma unroll
        for (int r4 = 0; r4 < 4; ++r4) sacc[mt][r4] = 0.f;

    // loop over hidden dim (N=128) in 4 chunks of 32; relu+W2 folded per chunk
#pragma unroll
    for (int nc = 0; nc < 4; ++nc) {
        bf16x8 bfr[2][2];
#pragma unroll
        for (int nt = 0; nt < 2; ++nt)
#pragma unroll
            for (int ks = 0; ks < 2; ++ks) {
                int d = nc * 32 + nt * 16 + lr;
                int kb = ks * 32 + lg * 8;
                const float* wp = W1 + (size_t)(w * CC + kb) * 128 + d;
                bf16x8 bv;
#pragma unroll
                for (int j = 0; j < 8; ++j) bv[j] = (short)f2bf(wp[(size_t)j * 128]);
                bfr[nt][ks] = bv;
            }
        f32x4 acc[4][2];
#pragma unroll
        for (int nt = 0; nt < 2; ++nt) {
            float b1v = b1[w * 128 + nc * 32 + nt * 16 + lr];
#pragma unroll
            for (int mt = 0; mt < 4; ++mt) {
                f32x4 ai = {b1v, b1v, b1v, b1v};
                acc[mt][nt] = ai;
            }
        }
#pragma unroll
        for (int mt = 0; mt < 4; ++mt)
#pragma unroll
            for (int nt = 0; nt < 2; ++nt)
#pragma unroll
                for (int ks = 0; ks < 2; ++ks)
                    acc[mt][nt] = __builtin_amdgcn_mfma_f32_16x16x32_bf16(
                        afr[mt][ks], bfr[nt][ks], acc[mt][nt], 0, 0, 0);
        float w2v0 = W2[w * 128 + nc * 32 + lr];
        float w2v1 = W2[w * 128 + nc * 32 + 16 + lr];
#pragma unroll
        for (int mt = 0; mt < 4; ++mt)
#pragma unroll
            for (int r4 = 0; r4 < 4; ++r4)
                sacc[mt][r4] += fmaxf(acc[mt][0][r4], 0.f) * w2v0
                              + fmaxf(acc[mt][1][r4], 0.f) * w2v1;
    }

    // reduce partial scores across the 16 column-lanes (xor butterfly within group)
#pragma unroll
    for (int off = 8; off > 0; off >>= 1)
#pragma unroll
        for (int mt = 0; mt < 4; ++mt)
#pragma unroll
            for (int r4 = 0; r4 < 4; ++r4)
                sacc[mt][r4] += __shfl_xor(sacc[mt][r4], off);

    if (lr == 0) {
        float b2v = b2[w];
#pragma unroll
        for (int mt = 0; mt < 4; ++mt)
#pragma unroll
            for (int r4 = 0; r4 < 4; ++r4) {
                // C/D layout: row = (lane>>4)*4 + reg
                int g = R + mt * 16 + lg * 4 + r4;
                if (g < NC_) score[(size_t)g * NH + w] = sacc[mt][r4] + b2v;
            }
    }
}

// ---------------- graph offsets (clique_batch is sorted) ----------------
__global__ void k_goff(const int* __restrict__ cb, int* __restrict__ goff) {
    int g = blockIdx.x * blockDim.x + threadIdx.x;
    if (g > NG) return;
    if (g == NG) { goff[g] = NC_; return; }
    int lo = 0, hi = NC_;
    while (lo < hi) { int mid = (lo + hi) >> 1; if (cb[mid] < g) lo = mid + 1; else hi = mid; }
    goff[g] = lo;
}

// ---------------- segment softmax + weighted segment-sum ----------------
__global__ __launch_bounds__(256) void k_soft(const float* __restrict__ score,
                                              const float* __restrict__ xc,
                                              const int* __restrict__ goff,
                                              float* __restrict__ alpha,
                                              float* __restrict__ df) {
    __shared__ float4 red[4];
    __shared__ float4 dfs[4][64];
    int g = blockIdx.x;
    int t = threadIdx.x, lane = t & 63, wid = t >> 6;
    int s = goff[g], e = goff[g + 1];

    // pass 1: per-head max
    float4 mx = make_float4(-INFINITY, -INFINITY, -INFINITY, -INFINITY);
    for (int i = s + t; i < e; i += 256) {
        float4 v = *reinterpret_cast<const float4*>(score + (size_t)i * 4);
        mx.x = fmaxf(mx.x, v.x); mx.y = fmaxf(mx.y, v.y);
        mx.z = fmaxf(mx.z, v.z); mx.w = fmaxf(mx.w, v.w);
    }
#pragma unroll
    for (int off = 32; off > 0; off >>= 1) {
        mx.x = fmaxf(mx.x, __shfl_down(mx.x, off));
        mx.y = fmaxf(mx.y, __shfl_down(mx.y, off));
        mx.z = fmaxf(mx.z, __shfl_down(mx.z, off));
        mx.w = fmaxf(mx.w, __shfl_down(mx.w, off));
    }
    if (lane == 0) red[wid] = mx;
    __syncthreads();
    {
        float4 a = red[0], b = red[1], c = red[2], d = red[3];
        mx.x = fmaxf(fmaxf(a.x, b.x), fmaxf(c.x, d.x));
        mx.y = fmaxf(fmaxf(a.y, b.y), fmaxf(c.y, d.y));
        mx.z = fmaxf(fmaxf(a.z, b.z), fmaxf(c.z, d.z));
        mx.w = fmaxf(fmaxf(a.w, b.w), fmaxf(c.w, d.w));
    }
    __syncthreads();

    // pass 2: per-head denom
    float4 dn = make_float4(0.f, 0.f, 0.f, 0.f);
    for (int i = s + t; i < e; i += 256) {
        float4 v = *reinterpret_cast<const float4*>(score + (size_t)i * 4);
        dn.x += expf(v.x - mx.x); dn.y += expf(v.y - mx.y);
        dn.z += expf(v.z - mx.z); dn.w += expf(v.w - mx.w);
    }
#pragma unroll
    for (int off = 32; off > 0; off >>= 1) {
        dn.x += __shfl_down(dn.x, off); dn.y += __shfl_down(dn.y, off);
        dn.z += __shfl_down(dn.z, off); dn.w += __shfl_down(dn.w, off);
    }
    if (lane == 0) red[wid] = dn;
    __syncthreads();
    {
        float4 a = red[0], b = red[1], c = red[2], d = red[3];
        dn.x = a.x + b.x + c.x + d.x; dn.y = a.y + b.y + c.y + d.y;
        dn.z = a.z + b.z + c.z + d.z; dn.w = a.w + b.w + c.w + d.w;
    }
    float4 inv;
    inv.x = 1.f / (dn.x + 1e-16f); inv.y = 1.f / (dn.y + 1e-16f);
    inv.z = 1.f / (dn.z + 1e-16f); inv.w = 1.f / (dn.w + 1e-16f);

    // pass 3: alpha + weighted accumulate (one wave per clique)
    float4 acc = make_float4(0.f, 0.f, 0.f, 0.f);
    int hsel = lane >> 4;
    for (int i = s + wid; i < e; i += 4) {
        float4 sv = *reinterpret_cast<const float4*>(score + (size_t)i * 4);
        float4 av;
        av.x = expf(sv.x - mx.x) * inv.x; av.y = expf(sv.y - mx.y) * inv.y;
        av.z = expf(sv.z - mx.z) * inv.z; av.w = expf(sv.w - mx.w) * inv.w;
        if (lane == 0) *reinterpret_cast<float4*>(alpha + (size_t)i * 4) = av;
        float a = (hsel == 0) ? av.x : (hsel == 1) ? av.y : (hsel == 2) ? av.z : av.w;
        float4 xv = *reinterpret_cast<const float4*>(xc + (size_t)i * DD + lane * 4);
        acc.x += xv.x * a; acc.y += xv.y * a; acc.z += xv.z * a; acc.w += xv.w * a;
    }
    dfs[wid][lane] = acc;
    __syncthreads();
    if (wid == 0) {
        float4 a = dfs[0][lane], b = dfs[1][lane], c = dfs[2][lane], d = dfs[3][lane];
        float4 r;
        r.x = a.x + b.x + c.x + d.x; r.y = a.y + b.y + c.y + d.y;
        r.z = a.z + b.z + c.z + d.z; r.w = a.w + b.w + c.w + d.w;
        *reinterpret_cast<float4*>(df + (size_t)g * DD + lane * 4) = r;
    }
}

extern "C" void kernel_launch(void* const* d_in, const int* in_sizes, int n_in,
                              void* d_out, int out_size, void* d_ws, size_t ws_size,
                              hipStream_t stream) {
    const float* x        = (const float*)d_in[0];
    const float* x_clique = (const float*)d_in[1];
    const float* Wp       = (const float*)d_in[2];
    const float* bp       = (const float*)d_in[3];
    const float* W1       = (const float*)d_in[4];
    const float* b1       = (const float*)d_in[5];
    const float* W2       = (const float*)d_in[6];
    const float* b2       = (const float*)d_in[7];
    const int*   a2c      = (const int*)d_in[8];
    const int*   cb       = (const int*)d_in[9];
    const int*   row = a2c;         // atom indices
    const int*   col = a2c + NE_;   // clique indices

    float* out_df    = (float*)d_out;
    float* out_xc    = out_df + (size_t)NG * DD;
    float* out_alpha = out_xc + (size_t)NC_ * DD;

    char* w = (char*)d_ws;
    int* cnt     = (int*)w;  w += (size_t)NC_ * 4;
    int* cursor  = (int*)w;  w += (size_t)NC_ * 4;
    int* offsets = (int*)w;  w += 1000016;            // (NC_+1)*4 rounded to 16
    int* edge_atom = (int*)w; w += (size_t)NE_ * 4;
    int* bsums   = (int*)w;  w += 1024;
    int* goff    = (int*)w;  w += 8208;               // (NG+1)*4 rounded to 16
    float* score = (float*)w; w += (size_t)NC_ * NH * 4;
    ushort_t* hx = (ushort_t*)w; w += (size_t)NC_ * DD * 2;

    hipMemsetAsync(cnt, 0, (size_t)2 * NC_ * 4, stream);   // cnt + cursor

    k_hist<<<(NE_ + 255) / 256, 256, 0, stream>>>(col, cnt);
    k_scan1<<<SCAN_NB, SCAN_T, 0, stream>>>(cnt, bsums);
    k_scan2<<<1, SCAN_T, 0, stream>>>(bsums, SCAN_NB);
    k_scan3<<<SCAN_NB, SCAN_T, 0, stream>>>(cnt, bsums, offsets);
    k_scatter<<<(NE_ + 255) / 256, 256, 0, stream>>>(row, col, offsets, cursor, edge_atom);
    k_mean<<<(NC_ + 3) / 4, 256, 0, stream>>>(x, offsets, edge_atom, hx);

    dim3 gg(DD / BN, (NC_ + BM - 1) / BM);
    k_gemm<<<gg, 256, 0, stream>>>(hx, Wp, bp, x_clique, out_xc);

    k_score<<<(NC_ + SROWS - 1) / SROWS, 256, 0, stream>>>(out_xc, W1, b1, W2, b2, score);
    k_goff<<<(NG + 1 + 255) / 256, 256, 0, stream>>>(cb, goff);
    k_soft<<<NG, 256, 0, stream>>>(score, out_xc, goff, out_alpha, out_df);
}